// Round 4
// baseline (3128.912 us; speedup 1.0000x reference)
//
#include <hip/hip_runtime.h>

#define NLAYER 6
#define NB     128     // batch
#define NT     512     // seq len
#define DIN    128     // layer-0 input size
#define NH     256     // hidden
#define NBLK   192     // 6 layers x 8 batch-groups x 4 blocks
// Tagged ring: each h value is one 4B word = (bf16<<16)|step_tag.
// Slot = [128 batch rows][256 words] = 128KB = 16384 u64. Plane (one bg) =
// 16 rows x 1KB = 16KB = 2048 u64.
#define TSLOT_U64 (NB*NH/2)
#define LPITCH64  70           // LDS plane row pitch in u64 (560B: 12-mod-32 banks)

typedef __attribute__((ext_vector_type(8))) short short8;
typedef __attribute__((ext_vector_type(4))) float f32x4;
typedef __attribute__((ext_vector_type(4))) unsigned uint4v;
typedef unsigned long long u64;

__device__ __forceinline__ unsigned f2bf2(float lo, float hi){
  unsigned a = __float_as_uint(lo), b = __float_as_uint(hi);
  a = (a + 0x7fffu + ((a>>16)&1u)) >> 16;   // RNE bf16
  b = (b + 0x7fffu + ((b>>16)&1u)) >> 16;
  return a | (b<<16);
}
__device__ __forceinline__ u64 f2bf4(float a, float b, float c, float d){
  return (u64)f2bf2(a,b) | ((u64)f2bf2(c,d) << 32);
}
__device__ __forceinline__ short8 pack16(u64 lo, u64 hi){
  union { u64 u[2]; short8 v; } w; w.u[0]=lo; w.u[1]=hi; return w.v;
}
// 8 consecutive fp32 -> one MFMA bf16 fragment (4 VGPRs)
__device__ __forceinline__ short8 ld8f_frag(const float* p){
  f32x4 a = *(const f32x4*)p;
  f32x4 b = *(const f32x4*)(p+4);
  return pack16(f2bf4(a[0],a[1],a[2],a[3]), f2bf4(b[0],b[1],b[2],b[3]));
}

__device__ __forceinline__ float sigmf(float v){ return 1.0f/(1.0f + __expf(-v)); }
__device__ __forceinline__ float tanhfast(float v){
  v = fminf(fmaxf(v, -15.0f), 15.0f);
  float e = __expf(2.0f*v);
  return (e - 1.0f)/(e + 1.0f);
}

// agent-scope (fabric-coherent) flag ops — rare paths only (acks)
__device__ __forceinline__ int ld_flag(const int* p){
  return __hip_atomic_load(p, __ATOMIC_RELAXED, __HIP_MEMORY_SCOPE_AGENT);
}
__device__ __forceinline__ void st_flag(int* p, int v){
  __hip_atomic_store(p, v, __ATOMIC_RELAXED, __HIP_MEMORY_SCOPE_AGENT);
}

// one h value + step tag -> self-validating 4B word
__device__ __forceinline__ unsigned tagw(float f, unsigned tag){
  unsigned a = __float_as_uint(f);
  return ((a + 0x7fffu + ((a>>16)&1u)) & 0xffff0000u) | tag;   // RNE bf16 in hi16
}
// strip tags: one tagged u64 (2 words) -> one packed u32 (2 bf16)
__device__ __forceinline__ unsigned strip2(u64 q){
  return __builtin_amdgcn_perm((unsigned)(q>>32), (unsigned)q, 0x07060302u);
}

// ---- raw cache-scoped plane samples -------------------------------------
// Fast path: sc0 = L1-bypass, served by the XCD L2. A producer's sc0 store
// on the same XCD dirties that L2 -> ~200-300cy detect. NOT coherent
// cross-XCD (consumer L2 may cache stale) — tags + the sc01 escape below
// make that a slowdown, never a correctness issue.
__device__ __forceinline__ void ld4x16_sc0(const u64* base, uint4v q[4]){
  asm volatile(
    "global_load_dwordx4 %0, %4, off sc0\n\t"
    "global_load_dwordx4 %1, %4, off offset:1024 sc0\n\t"
    "global_load_dwordx4 %2, %4, off offset:2048 sc0\n\t"
    "global_load_dwordx4 %3, %4, off offset:3072 sc0\n\t"
    "s_waitcnt vmcnt(0)"
    : "=&v"(q[0]), "=&v"(q[1]), "=&v"(q[2]), "=&v"(q[3])
    : "v"(base) : "memory");
}
// Escape path: sc0 sc1 = fabric-coherent sample (authoritative).
__device__ __forceinline__ void ld4x16_sc01(const u64* base, uint4v q[4]){
  asm volatile(
    "global_load_dwordx4 %0, %4, off sc0 sc1\n\t"
    "global_load_dwordx4 %1, %4, off offset:1024 sc0 sc1\n\t"
    "global_load_dwordx4 %2, %4, off offset:2048 sc0 sc1\n\t"
    "global_load_dwordx4 %3, %4, off offset:3072 sc0 sc1\n\t"
    "s_waitcnt vmcnt(0)"
    : "=&v"(q[0]), "=&v"(q[1]), "=&v"(q[2]), "=&v"(q[3])
    : "v"(base) : "memory");
}
// Dual publish: sc1 leg writes through to the fabric (guaranteed global
// visibility), sc0 leg dirties the local L2 (fast same-XCD detect).
__device__ __forceinline__ void st16_pub(u64* p, uint4v v){
  asm volatile(
    "global_store_dwordx4 %0, %1, off sc0 sc1\n\t"
    "global_store_dwordx4 %0, %1, off sc0"
    :: "v"(p), "v"(v) : "memory");
}

// Poll one 16-row tagged plane (this wave stages rows wv*4..wv*4+3, 16B/lane,
// fully coalesced), validate embedded tags, strip, write packed bf16 to LDS.
__device__ __forceinline__ void poll_stage(const u64* __restrict__ src, unsigned tag,
                                           u64* __restrict__ ldsPlane, int wv, int lane){
  const u64* base = src + (size_t)wv*512 + (size_t)lane*2;
  uint4v q[4];
  int it = 0, guard = 0;
  for (;;){
    ++it;
    if (it > 3 && (it & 1)) ld4x16_sc01(base, q);
    else                    ld4x16_sc0(base, q);
    unsigned bad = 0;
    #pragma unroll
    for (int c = 0; c < 4; ++c){
      uint4v xq = q[c] ^ tag;
      bad |= xq[0] | xq[1] | xq[2] | xq[3];
    }
    if (__ballot((bad & 0xffffu) == 0u) == ~0ull) break;
    if (++guard > (1<<22)) break;   // failsafe only
  }
  u64* lp = ldsPlane + (size_t)(wv*4)*LPITCH64 + lane;
  #pragma unroll
  for (int c = 0; c < 4; ++c){
    union { uint4v v; u64 d[2]; } uq; uq.v = q[c];
    lp[c*LPITCH64] = (u64)strip2(uq.d[0]) | ((u64)strip2(uq.d[1]) << 32);
  }
}

// MFMA B-fragment from a staged LDS plane (row pitch 280 shorts = 560B:
// 12-mod-32 bank stagger -> 2-way (free) on ds_read_b128 across rows).
__device__ __forceinline__ short8 lds_frag(const u64* __restrict__ buf, int row, int soff){
  return *(const short8*)((const short*)buf + row*280 + soff);
}

// Block = 4 slices x 16 batch rows. Phase-X (slack edge) then phase-H
// (critical edge) per step; h-visibility hides under x-compute.
template<int NKX>
__device__ __forceinline__ void lstm_run(
    const float* __restrict__ x,  const float* __restrict__ h0,
    const float* __restrict__ c0, const float* __restrict__ wx,
    const float* __restrict__ wh, const float* __restrict__ bi,
    const float* __restrict__ bh, float* __restrict__ out,
    int* __restrict__ acks, u64* __restrict__ ring, u64 (*ldsb)[16*LPITCH64],
    int Wv, int l, int bg, int s, int wv, int lane)
{
  constexpr int KIT  = NKX + 8;      // total k-iterations (12 or 16)
  constexpr int KX   = NKX*32;       // input width (128 or 256)
  constexpr bool HASX = (NKX == 8);  // x comes from the prev-layer ring
  const int l15  = lane & 15;
  const int quad = lane >> 4;
  const int bloc = bg*16 + l15;      // this lane's batch row
  const int jcol = s*16 + quad*4;    // this lane's first hidden col
  const int Wm   = Wv - 1;

  // ---- A fragments: stationary (4 gates x KIT kts x 4 VGPR) ----
  short8 A[4][KIT];
  #pragma unroll
  for (int q = 0; q < 4; ++q){
    const float* wrow_x = wx + (size_t)(q*NH + s*16 + l15)*KX;
    const float* wrow_h = wh + (size_t)(q*NH + s*16 + l15)*NH;
    #pragma unroll
    for (int kt = 0; kt < KIT; ++kt){
      int k0 = kt*32 + quad*8;
      A[q][kt] = (k0 < KX) ? ld8f_frag(wrow_x + k0)
                           : ld8f_frag(wrow_h + (k0 - KX));
    }
  }

  f32x4 bsv[4];
  #pragma unroll
  for (int q = 0; q < 4; ++q){
    f32x4 a = *(const f32x4*)(bi + q*NH + jcol);
    f32x4 b = *(const f32x4*)(bh + q*NH + jcol);
    bsv[q] = a + b;
  }
  float cc[4];
  {
    f32x4 cv = *(const f32x4*)(c0 + ((size_t)l*NB + bloc)*NH + jcol);
    cc[0]=cv[0]; cc[1]=cv[1]; cc[2]=cv[2]; cc[3]=cv[3];
  }

  const int* ackOwn = acks + (l*8 + bg)*16;                     // layer l+1 watermarks
  int* ackPrevW = HASX ? acks + ((l-1)*8 + bg)*16 + s : nullptr;
  const u64* ringPrev = HASX ? ring + (size_t)(l-1)*Wv*TSLOT_U64 : nullptr;
  u64*       ringOwn  = ring + (size_t)l*Wv*TSLOT_U64;
  const bool lastL = (l == NLAYER-1);
  const bool wrap  = (Wv < NT);
  int ackmin = 0;

  for (int t = 0; t < NT; ++t){
    const int slot  = t & Wm;
    const int pslot = (t-1) & Wm;

    // WAR guard (wrap only): layer l+1 must have consumed slot t-Wv.
    if (wrap && !lastL && t >= Wv){
      const int need = t - Wv + 1;
      if (ackmin < need){
        int v = 0, guard = 0;
        for (;;){
          v = (lane < 16) ? ld_flag(ackOwn + lane) : 0x7fffffff;
          if (__ballot(v >= need) == ~0ull) break;
          __builtin_amdgcn_s_sleep(1);
          if (++guard > (1<<22)) break;
        }
        int m = v;
        #pragma unroll
        for (int o = 8; o; o >>= 1) m = min(m, __shfl_xor(m, o));
        ackmin = __shfl(m, 0);
      }
    }

    // ================= phase X (slack edge) =================
    u64* ldsX = ldsb[(t&1)*2 + 0];
    u64* ldsH = ldsb[(t&1)*2 + 1];
    short8 Bx[NKX];
    if constexpr (HASX){
      poll_stage(ringPrev + (size_t)slot*TSLOT_U64 + bg*2048, (unsigned)(t+1),
                 ldsX, wv, lane);
      __syncthreads();
      // ack prev-layer slot consumed (stage values were tag-checked -> done)
      if (wrap && ((t & 7) == 7) && lane == 0) st_flag(ackPrevW, t+1);
      #pragma unroll
      for (int k = 0; k < NKX; ++k) Bx[k] = lds_frag(ldsX, l15, quad*8 + k*32);
    } else {
      const float* px = x + ((size_t)bloc*NT + t)*DIN + quad*8;
      #pragma unroll
      for (int k = 0; k < NKX; ++k) Bx[k] = ld8f_frag(px + k*32);
    }

    // x-part MFMAs run while the cohort's h_t-1 publish propagates
    f32x4 a0 = {0,0,0,0}, a1 = {0,0,0,0}, a2 = {0,0,0,0}, a3 = {0,0,0,0};
    #pragma unroll
    for (int k = 0; k < NKX; ++k){
      a0 = __builtin_amdgcn_mfma_f32_16x16x32_bf16(A[0][k], Bx[k], a0, 0, 0, 0);
      a1 = __builtin_amdgcn_mfma_f32_16x16x32_bf16(A[1][k], Bx[k], a1, 0, 0, 0);
      a2 = __builtin_amdgcn_mfma_f32_16x16x32_bf16(A[2][k], Bx[k], a2, 0, 0, 0);
      a3 = __builtin_amdgcn_mfma_f32_16x16x32_bf16(A[3][k], Bx[k], a3, 0, 0, 0);
    }

    // ================= phase H (critical edge) =================
    short8 Bh[8];
    if (t == 0){
      const float* ph = h0 + ((size_t)l*NB + bloc)*NH + quad*8;
      #pragma unroll
      for (int k = 0; k < 8; ++k) Bh[k] = ld8f_frag(ph + k*32);
    } else {
      poll_stage(ringOwn + (size_t)pslot*TSLOT_U64 + bg*2048, (unsigned)t,
                 ldsH, wv, lane);
      __syncthreads();
      #pragma unroll
      for (int k = 0; k < 8; ++k) Bh[k] = lds_frag(ldsH, l15, quad*8 + k*32);
    }
    #pragma unroll
    for (int k = 0; k < 8; ++k){
      a0 = __builtin_amdgcn_mfma_f32_16x16x32_bf16(A[0][NKX+k], Bh[k], a0, 0, 0, 0);
      a1 = __builtin_amdgcn_mfma_f32_16x16x32_bf16(A[1][NKX+k], Bh[k], a1, 0, 0, 0);
      a2 = __builtin_amdgcn_mfma_f32_16x16x32_bf16(A[2][NKX+k], Bh[k], a2, 0, 0, 0);
      a3 = __builtin_amdgcn_mfma_f32_16x16x32_bf16(A[3][NKX+k], Bh[k], a3, 0, 0, 0);
    }

    // ---- fused gate nonlinearities + state update ----
    float hv[4];
    #pragma unroll
    for (int r = 0; r < 4; ++r){
      float ig = sigmf(a0[r] + bsv[0][r]);
      float fg = sigmf(a1[r] + bsv[1][r]);
      float gv = tanhfast(a2[r] + bsv[2][r]);
      float og = sigmf(a3[r] + bsv[3][r]);
      float cn = fg*cc[r] + ig*gv;
      cc[r] = cn;
      hv[r] = og * tanhfast(cn);
    }

    // ---- publish: one 16B self-tagged dual store (fabric + local L2) ----
    {
      const unsigned otag = (unsigned)(t+1);
      uint4v pv;
      pv[0] = tagw(hv[0], otag); pv[1] = tagw(hv[1], otag);
      pv[2] = tagw(hv[2], otag); pv[3] = tagw(hv[3], otag);
      st16_pub(ringOwn + (size_t)slot*TSLOT_U64 + (size_t)bloc*128 + s*8 + quad*2, pv);
    }
    if (t == NT-1){
      f32x4 ov; ov[0]=hv[0]; ov[1]=hv[1]; ov[2]=hv[2]; ov[3]=hv[3];
      *(f32x4*)(out + ((size_t)l*NB + bloc)*NH + jcol) = ov;
    }
  }
}

__global__ __launch_bounds__(256, 1)
void lstm_pipe(const float* __restrict__ x,   const float* __restrict__ h0,
               const float* __restrict__ c0,  const float* __restrict__ wih0,
               const float* __restrict__ wih, const float* __restrict__ whh,
               const float* __restrict__ bih, const float* __restrict__ bhh,
               float* __restrict__ out, int* __restrict__ acks,
               u64* __restrict__ ring, int Wv)
{
  // XCD clustering: bid = bg + 8*(l*4 + b) -> with bid%8 XCD round-robin the
  // whole pipeline of batch-group bg (24 blocks) shares one XCD/L2. This is
  // a speed heuristic only: the sc01 escape keeps any mapping correct.
  __shared__ u64 ldsb[4][16*LPITCH64];   // [buf2][x/h][16 rows x 560B]
  const int bid  = blockIdx.x;
  const int bg   = bid & 7;
  const int j    = bid >> 3;
  const int l    = j >> 2;
  const int b    = j & 3;
  const int lane = threadIdx.x & 63;
  const int wv   = threadIdx.x >> 6;
  const int s    = b*4 + wv;          // this wave's slice (0..15)

  if (l == 0)
    lstm_run<4>(x, h0, c0, wih0, whh, bih, bhh,
                out, acks, ring, ldsb, Wv, 0, bg, s, wv, lane);
  else
    lstm_run<8>(x, h0, c0,
                wih + (size_t)(l-1)*(4*NH*NH),
                whh + (size_t)l*(4*NH*NH),
                bih + (size_t)l*(4*NH),
                bhh + (size_t)l*(4*NH),
                out, acks, ring, ldsb, Wv, l, bg, s, wv, lane);
}

extern "C" void kernel_launch(void* const* d_in, const int* in_sizes, int n_in,
                              void* d_out, int out_size, void* d_ws, size_t ws_size,
                              hipStream_t stream)
{
  (void)in_sizes; (void)n_in; (void)out_size;
  const float* x    = (const float*)d_in[0];
  const float* h0   = (const float*)d_in[1];
  const float* c0   = (const float*)d_in[2];
  const float* wih0 = (const float*)d_in[3];
  const float* wih  = (const float*)d_in[4];
  const float* whh  = (const float*)d_in[5];
  const float* bih  = (const float*)d_in[6];
  const float* bhh  = (const float*)d_in[7];

  // Ring depth 32 (25 MB tagged). Own-h cohort is lockstep (skew <= 1);
  // cross-layer wrap uses amortized acks.
  int Wv = 32;
  size_t ringB;
  for (;;){
    ringB = (size_t)NLAYER*Wv*TSLOT_U64*8;
    if (8192 + ringB <= ws_size || Wv <= 8) break;
    Wv >>= 1;
  }

  int* acks = (int*)d_ws;                    // 768 ints, padded to 8KB
  u64* ring = (u64*)((char*)d_ws + 8192);

  // Ring MUST be cleared every launch: graph replay would otherwise find the
  // previous run's tags (identical t+1 pattern) and accept stale data.
  // Tag 0 never validates (expected tags are >= 1).
  (void)hipMemsetAsync(d_ws, 0, 8192 + ringB, stream);
  hipLaunchKernelGGL(lstm_pipe, dim3(NBLK), dim3(256), 0, stream,
                     x, h0, c0, wih0, wih, whh, bih, bhh,
                     (float*)d_out, acks, ring, Wv);
}

// Round 5
// 2222.591 us; speedup vs baseline: 1.4078x; 1.4078x over previous
//
#include <hip/hip_runtime.h>

#define NLAYER 6
#define NB     128     // batch
#define NT     512     // seq len
#define DIN    128     // layer-0 input size
#define NH     256     // hidden
#define NBLK   192     // 6 layers x 8 batch-groups x 4 blocks
// Tagged ring: each h value is one 4B word = (bf16<<16)|step_tag.
// Slot = [128 batch rows][256 words] = 128KB = 16384 u64. Plane (one bg) =
// 16 rows x 1KB = 2048 u64.
#define TSLOT_U64 (NB*NH/2)

typedef __attribute__((ext_vector_type(8))) short short8;
typedef __attribute__((ext_vector_type(4))) float f32x4;
typedef __attribute__((ext_vector_type(4))) unsigned uint4v;
typedef unsigned long long u64;

__device__ __forceinline__ unsigned f2bf2(float lo, float hi){
  unsigned a = __float_as_uint(lo), b = __float_as_uint(hi);
  a = (a + 0x7fffu + ((a>>16)&1u)) >> 16;   // RNE bf16
  b = (b + 0x7fffu + ((b>>16)&1u)) >> 16;
  return a | (b<<16);
}
__device__ __forceinline__ u64 f2bf4(float a, float b, float c, float d){
  return (u64)f2bf2(a,b) | ((u64)f2bf2(c,d) << 32);
}
__device__ __forceinline__ short8 pack16(u64 lo, u64 hi){
  union { u64 u[2]; short8 v; } w; w.u[0]=lo; w.u[1]=hi; return w.v;
}
// 8 consecutive fp32 -> one MFMA bf16 fragment (4 VGPRs)
__device__ __forceinline__ short8 ld8f_frag(const float* p){
  f32x4 a = *(const f32x4*)p;
  f32x4 b = *(const f32x4*)(p+4);
  return pack16(f2bf4(a[0],a[1],a[2],a[3]), f2bf4(b[0],b[1],b[2],b[3]));
}

__device__ __forceinline__ float sigmf(float v){ return 1.0f/(1.0f + __expf(-v)); }
__device__ __forceinline__ float tanhfast(float v){
  v = fminf(fmaxf(v, -15.0f), 15.0f);
  float e = __expf(2.0f*v);
  return (e - 1.0f)/(e + 1.0f);
}

// agent-scope (fabric-coherent) flag ops — rare paths only (WAR acks)
__device__ __forceinline__ int ld_flag(const int* p){
  return __hip_atomic_load(p, __ATOMIC_RELAXED, __HIP_MEMORY_SCOPE_AGENT);
}
__device__ __forceinline__ void st_flag(int* p, int v){
  __hip_atomic_store(p, v, __ATOMIC_RELAXED, __HIP_MEMORY_SCOPE_AGENT);
}

// one h value + step tag -> self-validating 4B word
__device__ __forceinline__ unsigned tagw(float f, unsigned tag){
  unsigned a = __float_as_uint(f);
  return ((a + 0x7fffu + ((a>>16)&1u)) & 0xffff0000u) | tag;   // RNE bf16 in hi16
}
// strip tags: one tagged u64 (2 words) -> one packed u32 (2 bf16)
__device__ __forceinline__ unsigned strip2(u64 q){
  return __builtin_amdgcn_perm((unsigned)(q>>32), (unsigned)q, 0x07060302u);
}

// ---- cache-policy-controlled plane samples -------------------------------
// FAST sample: caller has just issued buffer_inv sc0 (L1 invalidate), so
// these PLAIN loads are served by the XCD L2 — which the producer's sc0
// store leg dirtied. Same-XCD handoff without any fabric round trip.
__device__ __forceinline__ void ld4x16_fast(const u64* base, uint4v q[4]){
  asm volatile(
    "global_load_dwordx4 %0, %4, off\n\t"
    "global_load_dwordx4 %1, %4, off offset:1024\n\t"
    "global_load_dwordx4 %2, %4, off offset:2048\n\t"
    "global_load_dwordx4 %3, %4, off offset:3072\n\t"
    "s_waitcnt vmcnt(0)"
    : "=&v"(q[0]), "=&v"(q[1]), "=&v"(q[2]), "=&v"(q[3])
    : "v"(base) : "memory");
}
// AUTHORITATIVE sample: sc0 sc1 bypasses L1+L2, reads the fabric/MALL copy.
// Guarantees progress even if producer and consumer sit on different XCDs.
__device__ __forceinline__ void ld4x16_auth(const u64* base, uint4v q[4]){
  asm volatile(
    "global_load_dwordx4 %0, %4, off sc0 sc1\n\t"
    "global_load_dwordx4 %1, %4, off offset:1024 sc0 sc1\n\t"
    "global_load_dwordx4 %2, %4, off offset:2048 sc0 sc1\n\t"
    "global_load_dwordx4 %3, %4, off offset:3072 sc0 sc1\n\t"
    "s_waitcnt vmcnt(0)"
    : "=&v"(q[0]), "=&v"(q[1]), "=&v"(q[2]), "=&v"(q[3])
    : "v"(base) : "memory");
}
// Dual publish: sc1 leg writes through to the fabric (authoritative copy,
// cross-XCD correctness); sc0 leg dirties the local L2 (fast same-XCD detect).
__device__ __forceinline__ void st16_pub(u64* p, uint4v v){
  asm volatile(
    "global_store_dwordx4 %0, %1, off sc0 sc1\n\t"
    "global_store_dwordx4 %0, %1, off sc0"
    :: "v"(p), "v"(v) : "memory");
}

// MFMA B-fragment from a staged LDS plane (row pitch 132 u32 = 528B).
__device__ __forceinline__ short8 lds_frag(const unsigned* __restrict__ buf, int row, int soff){
  return *(const short8*)((const short*)buf + row*264 + soff);
}

// Block = 4 slices x 16 batch rows. Wave wv owns slice s = b*4+wv. h/x are
// staged once per block into LDS via POLLING tagged loads (the stage IS the
// sync); A stationary in regs; publish is fire-and-forget dual-scope stores.
template<int NKX>
__device__ __forceinline__ void lstm_run(
    const float* __restrict__ x,  const float* __restrict__ h0,
    const float* __restrict__ c0, const float* __restrict__ wx,
    const float* __restrict__ wh, const float* __restrict__ bi,
    const float* __restrict__ bh, float* __restrict__ out,
    int* __restrict__ acks, u64* __restrict__ ring, unsigned (*ldsb)[2112],
    int Wv, int l, int bg, int s, int wv, int lane)
{
  constexpr int KIT  = NKX + 8;      // total k-iterations (12 or 16)
  constexpr int KX   = NKX*32;       // input width (128 or 256)
  constexpr bool HASX = (NKX == 8);  // x comes from the prev-layer ring
  const int l15  = lane & 15;
  const int quad = lane >> 4;
  const int bloc = bg*16 + l15;      // this lane's batch row
  const int jcol = s*16 + quad*4;    // this lane's first hidden col
  const int Wm   = Wv - 1;

  // ---- A fragments: stationary (4 gates x KIT kts x 4 VGPR) ----
  short8 A[4][KIT];
  #pragma unroll
  for (int q = 0; q < 4; ++q){
    const float* wrow_x = wx + (size_t)(q*NH + s*16 + l15)*KX;
    const float* wrow_h = wh + (size_t)(q*NH + s*16 + l15)*NH;
    #pragma unroll
    for (int kt = 0; kt < KIT; ++kt){
      int k0 = kt*32 + quad*8;
      A[q][kt] = (k0 < KX) ? ld8f_frag(wrow_x + k0)
                           : ld8f_frag(wrow_h + (k0 - KX));
    }
  }

  f32x4 bsv[4];
  #pragma unroll
  for (int q = 0; q < 4; ++q){
    f32x4 a = *(const f32x4*)(bi + q*NH + jcol);
    f32x4 b = *(const f32x4*)(bh + q*NH + jcol);
    bsv[q] = a + b;
  }
  float cc[4];
  {
    f32x4 cv = *(const f32x4*)(c0 + ((size_t)l*NB + bloc)*NH + jcol);
    cc[0]=cv[0]; cc[1]=cv[1]; cc[2]=cv[2]; cc[3]=cv[3];
  }

  const int* ackOwn = acks + (l*8 + bg)*16;                     // layer l+1 watermarks
  int* ackPrevW = HASX ? acks + ((l-1)*8 + bg)*16 + s : nullptr;
  const u64* ringPrev = HASX ? ring + (size_t)(l-1)*Wv*TSLOT_U64 : nullptr;
  u64*       ringOwn  = ring + (size_t)l*Wv*TSLOT_U64;
  const bool lastL = (l == NLAYER-1);
  const bool wrap  = (Wv < NT);
  int ackmin = 0;

  for (int t = 0; t < NT; ++t){
    const int slot  = t & Wm;
    const int pslot = (t-1) & Wm;

    // WAR guard (wrap only): layer l+1 must have consumed slot t-Wv.
    // Consumers ack every 8 steps; cached watermark -> fabric poll ~1/8 steps.
    if (wrap && !lastL && t >= Wv){
      const int need = t - Wv + 1;
      if (ackmin < need){
        int v = 0, guard = 0;
        for (;;){
          v = (lane < 16) ? ld_flag(ackOwn + lane) : 0x7fffffff;
          if (__ballot(v >= need) == ~0ull) break;
          __builtin_amdgcn_s_sleep(1);
          if (++guard > (1<<22)) break;
        }
        int m = v;
        #pragma unroll
        for (int o = 8; o; o >>= 1) m = min(m, __shfl_xor(m, o));
        ackmin = __shfl(m, 0);
      }
    }

    short8 Bx[NKX];
    if constexpr (!HASX){
      // layer 0: x is a plain cached load, consumed into regs BEFORE any
      // L1 invalidation inside the spin
      const float* px = x + ((size_t)bloc*NT + t)*DIN + quad*8;
      #pragma unroll
      for (int k = 0; k < NKX; ++k) Bx[k] = ld8f_frag(px + k*32);
    }

    // ---- polling stage: L1-inv + plain loads (L2-served fast path),
    // sc0 sc1 authoritative sample every 4th iteration ----
    const u64* srcX = HASX ? ringPrev + (size_t)slot*TSLOT_U64 + bg*2048 : nullptr;
    const u64* srcH = (t > 0) ? ringOwn + (size_t)pslot*TSLOT_U64 + bg*2048 : nullptr;
    unsigned* ldsX = ldsb[(t&1)*2 + 0];
    unsigned* ldsH = ldsb[(t&1)*2 + 1];
    const u64* bx = HASX ? srcX + (size_t)wv*512 + (size_t)lane*2 : nullptr;
    const u64* bh = srcH ? srcH + (size_t)wv*512 + (size_t)lane*2 : nullptr;
    uint4v qx[4], qh[4];
    {
      bool okx = !HASX, okh = (srcH == nullptr);
      const unsigned xtag = (unsigned)(t+1), htag = (unsigned)t;
      int it = 0, guard = 0;
      while (!(okx & okh)){
        ++it;
        const bool auth = (it >= 4) && ((it & 3) == 0);
        if (!auth) asm volatile("buffer_inv sc0" ::: "memory");  // L1 inv -> L2-fresh
        if (!okx){ if (auth) ld4x16_auth(bx, qx); else ld4x16_fast(bx, qx); }
        if (!okh){ if (auth) ld4x16_auth(bh, qh); else ld4x16_fast(bh, qh); }
        if (!okx){
          unsigned bad = 0;
          #pragma unroll
          for (int c = 0; c < 4; ++c){
            uint4v xq = qx[c] ^ xtag;
            bad |= xq[0] | xq[1] | xq[2] | xq[3];
          }
          okx = (__ballot((bad & 0xffffu) == 0u) == ~0ull);
        }
        if (!okh){
          unsigned bad = 0;
          #pragma unroll
          for (int c = 0; c < 4; ++c){
            uint4v xq = qh[c] ^ htag;
            bad |= xq[0] | xq[1] | xq[2] | xq[3];
          }
          okh = (__ballot((bad & 0xffffu) == 0u) == ~0ull);
        }
        if (okx & okh) break;
        if ((it & 15) == 15) __builtin_amdgcn_s_sleep(1);
        if (++guard > (1<<22)) break;   // failsafe only
      }
    }
    // strip tags -> packed bf16 planes in LDS (lane-contiguous: conflict-free)
    if constexpr (HASX){
      #pragma unroll
      for (int c = 0; c < 4; ++c){
        union { uint4v v; u64 d[2]; } uq; uq.v = qx[c];
        *(u64*)(ldsX + (wv*4+c)*132 + lane*2) =
            (u64)strip2(uq.d[0]) | ((u64)strip2(uq.d[1]) << 32);
      }
    }
    if (srcH){
      #pragma unroll
      for (int c = 0; c < 4; ++c){
        union { uint4v v; u64 d[2]; } uq; uq.v = qh[c];
        *(u64*)(ldsH + (wv*4+c)*132 + lane*2) =
            (u64)strip2(uq.d[0]) | ((u64)strip2(uq.d[1]) << 32);
      }
    }
    __syncthreads();

    // ack prev-layer consumption every 8 steps (values were tag-checked ->
    // loads complete; relaxed agent flag is sufficient for the WAR watermark)
    if (HASX && wrap && ((t & 7) == 7) && lane == 0) st_flag(ackPrevW, t+1);

    if constexpr (HASX){
      #pragma unroll
      for (int k = 0; k < NKX; ++k) Bx[k] = lds_frag(ldsX, l15, quad*8 + k*32);
    }
    short8 Bh[8];
    if (t == 0){
      const float* ph = h0 + ((size_t)l*NB + bloc)*NH + quad*8;
      #pragma unroll
      for (int k = 0; k < 8; ++k) Bh[k] = ld8f_frag(ph + k*32);
    } else {
      #pragma unroll
      for (int k = 0; k < 8; ++k) Bh[k] = lds_frag(ldsH, l15, quad*8 + k*32);
    }

    // ---- MFMAs: x-part then h-part ----
    f32x4 a0 = {0,0,0,0}, a1 = {0,0,0,0}, a2 = {0,0,0,0}, a3 = {0,0,0,0};
    #pragma unroll
    for (int k = 0; k < NKX; ++k){
      a0 = __builtin_amdgcn_mfma_f32_16x16x32_bf16(A[0][k], Bx[k], a0, 0, 0, 0);
      a1 = __builtin_amdgcn_mfma_f32_16x16x32_bf16(A[1][k], Bx[k], a1, 0, 0, 0);
      a2 = __builtin_amdgcn_mfma_f32_16x16x32_bf16(A[2][k], Bx[k], a2, 0, 0, 0);
      a3 = __builtin_amdgcn_mfma_f32_16x16x32_bf16(A[3][k], Bx[k], a3, 0, 0, 0);
    }
    #pragma unroll
    for (int k = 0; k < 8; ++k){
      a0 = __builtin_amdgcn_mfma_f32_16x16x32_bf16(A[0][NKX+k], Bh[k], a0, 0, 0, 0);
      a1 = __builtin_amdgcn_mfma_f32_16x16x32_bf16(A[1][NKX+k], Bh[k], a1, 0, 0, 0);
      a2 = __builtin_amdgcn_mfma_f32_16x16x32_bf16(A[2][NKX+k], Bh[k], a2, 0, 0, 0);
      a3 = __builtin_amdgcn_mfma_f32_16x16x32_bf16(A[3][NKX+k], Bh[k], a3, 0, 0, 0);
    }

    // ---- fused gate nonlinearities + state update ----
    float hv[4];
    #pragma unroll
    for (int r = 0; r < 4; ++r){
      float ig = sigmf(a0[r] + bsv[0][r]);
      float fg = sigmf(a1[r] + bsv[1][r]);
      float gv = tanhfast(a2[r] + bsv[2][r]);
      float og = sigmf(a3[r] + bsv[3][r]);
      float cn = fg*cc[r] + ig*gv;
      cc[r] = cn;
      hv[r] = og * tanhfast(cn);
    }

    // ---- publish: one 16B self-tagged dual-scope store (fabric + L2) ----
    {
      const unsigned otag = (unsigned)(t+1);
      uint4v pv;
      pv[0] = tagw(hv[0], otag); pv[1] = tagw(hv[1], otag);
      pv[2] = tagw(hv[2], otag); pv[3] = tagw(hv[3], otag);
      st16_pub(ringOwn + (size_t)slot*TSLOT_U64 + (size_t)bloc*128 + s*8 + quad*2, pv);
    }
    if (t == NT-1){
      f32x4 ov; ov[0]=hv[0]; ov[1]=hv[1]; ov[2]=hv[2]; ov[3]=hv[3];
      *(f32x4*)(out + ((size_t)l*NB + bloc)*NH + jcol) = ov;
    }
  }
}

__global__ __launch_bounds__(256, 1)
void lstm_pipe(const float* __restrict__ x,   const float* __restrict__ h0,
               const float* __restrict__ c0,  const float* __restrict__ wih0,
               const float* __restrict__ wih, const float* __restrict__ whh,
               const float* __restrict__ bih, const float* __restrict__ bhh,
               float* __restrict__ out, int* __restrict__ acks,
               u64* __restrict__ ring, int Wv)
{
  // XCD clustering: bid = bg + 8*(l*4 + b) -> with bid%8 XCD round-robin the
  // whole pipeline of batch-group bg (24 blocks) shares one XCD/L2. Speed
  // heuristic only: the sc0 sc1 authoritative samples keep any mapping correct.
  __shared__ unsigned ldsb[4][2112];   // [buf2][x/h][16 rows x 132 u32]
  const int bid  = blockIdx.x;
  const int bg   = bid & 7;
  const int j    = bid >> 3;
  const int l    = j >> 2;
  const int b    = j & 3;
  const int lane = threadIdx.x & 63;
  const int wv   = threadIdx.x >> 6;
  const int s    = b*4 + wv;          // this wave's slice (0..15)

  if (l == 0)
    lstm_run<4>(x, h0, c0, wih0, whh, bih, bhh,
                out, acks, ring, ldsb, Wv, 0, bg, s, wv, lane);
  else
    lstm_run<8>(x, h0, c0,
                wih + (size_t)(l-1)*(4*NH*NH),
                whh + (size_t)l*(4*NH*NH),
                bih + (size_t)l*(4*NH),
                bhh + (size_t)l*(4*NH),
                out, acks, ring, ldsb, Wv, l, bg, s, wv, lane);
}

extern "C" void kernel_launch(void* const* d_in, const int* in_sizes, int n_in,
                              void* d_out, int out_size, void* d_ws, size_t ws_size,
                              hipStream_t stream)
{
  (void)in_sizes; (void)n_in; (void)out_size;
  const float* x    = (const float*)d_in[0];
  const float* h0   = (const float*)d_in[1];
  const float* c0   = (const float*)d_in[2];
  const float* wih0 = (const float*)d_in[3];
  const float* wih  = (const float*)d_in[4];
  const float* whh  = (const float*)d_in[5];
  const float* bih  = (const float*)d_in[6];
  const float* bhh  = (const float*)d_in[7];

  // Ring depth 32 (25 MB tagged). Own-h cohort is lockstep (skew <= 1);
  // cross-layer wrap uses amortized acks.
  int Wv = 32;
  size_t ringB;
  for (;;){
    ringB = (size_t)NLAYER*Wv*TSLOT_U64*8;
    if (8192 + ringB <= ws_size || Wv <= 8) break;
    Wv >>= 1;
  }

  int* acks = (int*)d_ws;                    // 768 ints, padded to 8KB
  u64* ring = (u64*)((char*)d_ws + 8192);

  // Ring MUST be cleared every launch: graph replay would otherwise find the
  // previous run's tags (identical t+1 pattern) and accept stale data.
  // Tag 0 never validates (expected tags are >= 1).
  (void)hipMemsetAsync(d_ws, 0, 8192 + ringB, stream);
  hipLaunchKernelGGL(lstm_pipe, dim3(NBLK), dim3(256), 0, stream,
                     x, h0, c0, wih0, wih, whh, bih, bhh,
                     (float*)d_out, acks, ring, Wv);
}